// Round 1
// baseline (3318.106 us; speedup 1.0000x reference)
//
#include <hip/hip_runtime.h>
#include <math.h>

static constexpr int Bsz = 4, Sq = 2048, Dm = 1024, NH = 16, DHd = 64;
static constexpr int Mrows = Bsz * Sq;  // 8192
// ln(10000)/64
static constexpr float ROPE_LN = 0.14391156831212787f;

// ---------------------------------------------------------------------------
// Tiled NT GEMM: C[m,n] = sum_k A[m,k] * W[n,k]  (A: M x K, W: N x K, row-major)
// 64x64 tile per block, 256 threads, 4x4 micro-tile per thread.
// Optional RoPE epilogue (do_rope != 0): column n -> head dim dh = n & 63,
// position = m & (Sq-1).
// ---------------------------------------------------------------------------
__device__ __forceinline__ void gemm_tile_nt(
    const float* __restrict__ A, const float* __restrict__ W,
    float* __restrict__ C, int K, int N, int do_rope)
{
    __shared__ float As[64][16];
    __shared__ float Bs[16][65];   // [k][n], pad to 65 to break bank stride

    const int tid = threadIdx.x;
    const int tx = tid & 15, ty = tid >> 4;
    const int m0 = blockIdx.y * 64;
    const int n0 = blockIdx.x * 64;

    const int lr = tid >> 2;            // 0..63 : row within tile for staging
    const int kc = (tid & 3) * 4;       // 0..12 : k-chunk for staging

    float acc[4][4] = {{0.f, 0.f, 0.f, 0.f}, {0.f, 0.f, 0.f, 0.f},
                       {0.f, 0.f, 0.f, 0.f}, {0.f, 0.f, 0.f, 0.f}};

    for (int k0 = 0; k0 < K; k0 += 16) {
        const float4 a4 = *(const float4*)&A[(size_t)(m0 + lr) * K + k0 + kc];
        const float4 w4 = *(const float4*)&W[(size_t)(n0 + lr) * K + k0 + kc];
        __syncthreads();   // previous iteration's LDS reads done
        *(float4*)&As[lr][kc] = a4;
        Bs[kc + 0][lr] = w4.x;
        Bs[kc + 1][lr] = w4.y;
        Bs[kc + 2][lr] = w4.z;
        Bs[kc + 3][lr] = w4.w;
        __syncthreads();

        #pragma unroll
        for (int kk = 0; kk < 16; ++kk) {
            float av[4], bv[4];
            #pragma unroll
            for (int i = 0; i < 4; ++i) av[i] = As[ty + 16 * i][kk];
            #pragma unroll
            for (int j = 0; j < 4; ++j) bv[j] = Bs[kk][tx * 4 + j];
            #pragma unroll
            for (int i = 0; i < 4; ++i)
                #pragma unroll
                for (int j = 0; j < 4; ++j)
                    acc[i][j] = fmaf(av[i], bv[j], acc[i][j]);
        }
    }

    const int nbase = n0 + tx * 4;
    #pragma unroll
    for (int i = 0; i < 4; ++i) {
        const int m = m0 + ty + 16 * i;
        float v0 = acc[i][0], v1 = acc[i][1], v2 = acc[i][2], v3 = acc[i][3];
        if (do_rope) {
            const float pos = (float)(m & (Sq - 1));
            const int dh0 = nbase & (DHd - 1);           // even
            const float f0 = expf(-ROPE_LN * (float)dh0);
            const float f1 = expf(-ROPE_LN * (float)(dh0 + 2));
            const float a0 = pos * f0, a1 = pos * f1;
            const float c0 = cosf(a0), s0 = sinf(a0);
            const float c1 = cosf(a1), s1 = sinf(a1);
            const float e0 = v0 * c0 - v1 * s0, o0 = v0 * s0 + v1 * c0;
            const float e1 = v2 * c1 - v3 * s1, o1 = v2 * s1 + v3 * c1;
            v0 = e0; v1 = o0; v2 = e1; v3 = o1;
        }
        *(float4*)&C[(size_t)m * N + nbase] = make_float4(v0, v1, v2, v3);
    }
}

__global__ __launch_bounds__(256) void qkv_rope_kernel(
    const float* __restrict__ x,
    const float* __restrict__ Wq, const float* __restrict__ Wk,
    const float* __restrict__ Wv,
    float* __restrict__ Qo, float* __restrict__ Ko, float* __restrict__ Vo)
{
    const int z = blockIdx.z;
    const float* W = (z == 0) ? Wq : (z == 1) ? Wk : Wv;
    float* C = (z == 0) ? Qo : (z == 1) ? Ko : Vo;
    gemm_tile_nt(x, W, C, Dm, Dm, (z < 2) ? 1 : 0);
}

__global__ __launch_bounds__(256) void oproj_kernel(
    const float* __restrict__ HO, const float* __restrict__ Wo,
    float* __restrict__ out)
{
    gemm_tile_nt(HO, Wo, out, Dm, Dm, 0);
}

// ---------------------------------------------------------------------------
// Flash attention (causal). One block per (b, h, 64-row Q tile). 256 threads.
// Q/K/V are laid out as [B*S, D] with column d = h*64 + dh.
// Output head_out same layout (which equals reshape(B,S,D) of (B,S,H,DH)).
// ---------------------------------------------------------------------------
__global__ __launch_bounds__(256) void attn_kernel(
    const float* __restrict__ Q, const float* __restrict__ K,
    const float* __restrict__ V, float* __restrict__ HO)
{
    __shared__ float Qs[64][65];
    __shared__ float Ks[64][65];
    __shared__ float Vs[64][65];
    __shared__ float Ss[64][65];
    __shared__ float mrow[64], lrow[64], arow[64];

    const int tid = threadIdx.x;
    const int tx = tid & 15, ty = tid >> 4;
    const int qi = blockIdx.x, h = blockIdx.y, b = blockIdx.z;
    const int q0 = qi * 64;
    const size_t base = (size_t)b * Sq * Dm + (size_t)h * DHd;

    // stage Q tile
    #pragma unroll
    for (int rep = 0; rep < 16; ++rep) {
        const int idx = tid + rep * 256;
        const int r = idx >> 6, c = idx & 63;
        Qs[r][c] = Q[base + (size_t)(q0 + r) * Dm + c];
    }
    if (tid < 64) { mrow[tid] = -3.0e38f; lrow[tid] = 0.f; }
    float O[4][4] = {{0.f, 0.f, 0.f, 0.f}, {0.f, 0.f, 0.f, 0.f},
                     {0.f, 0.f, 0.f, 0.f}, {0.f, 0.f, 0.f, 0.f}};
    __syncthreads();

    for (int jt = 0; jt <= qi; ++jt) {
        const int t0 = jt * 64;
        // stage K, V tiles
        #pragma unroll
        for (int rep = 0; rep < 16; ++rep) {
            const int idx = tid + rep * 256;
            const int r = idx >> 6, c = idx & 63;
            Ks[r][c] = K[base + (size_t)(t0 + r) * Dm + c];
            Vs[r][c] = V[base + (size_t)(t0 + r) * Dm + c];
        }
        __syncthreads();

        // S = (Q K^T) * scale, causal-masked
        float sacc[4][4] = {{0.f, 0.f, 0.f, 0.f}, {0.f, 0.f, 0.f, 0.f},
                            {0.f, 0.f, 0.f, 0.f}, {0.f, 0.f, 0.f, 0.f}};
        #pragma unroll 8
        for (int kk = 0; kk < 64; ++kk) {
            float av[4], bv[4];
            #pragma unroll
            for (int i = 0; i < 4; ++i) av[i] = Qs[ty + 16 * i][kk];
            #pragma unroll
            for (int j = 0; j < 4; ++j) bv[j] = Ks[tx * 4 + j][kk];
            #pragma unroll
            for (int i = 0; i < 4; ++i)
                #pragma unroll
                for (int j = 0; j < 4; ++j)
                    sacc[i][j] = fmaf(av[i], bv[j], sacc[i][j]);
        }
        const bool diag = (jt == qi);
        #pragma unroll
        for (int i = 0; i < 4; ++i) {
            const int srow = q0 + ty + 16 * i;
            #pragma unroll
            for (int j = 0; j < 4; ++j) {
                const int tcol = t0 + tx * 4 + j;
                float v = sacc[i][j] * 0.125f;   // 1/sqrt(64)
                if (diag && tcol > srow) v = -3.0e38f;
                Ss[ty + 16 * i][tx * 4 + j] = v;
            }
        }
        __syncthreads();

        // row max + alpha
        if (tid < 64) {
            float mx = mrow[tid];
            #pragma unroll 8
            for (int t = 0; t < 64; ++t) mx = fmaxf(mx, Ss[tid][t]);
            arow[tid] = expf(mrow[tid] - mx);
            mrow[tid] = mx;
        }
        __syncthreads();

        // p = exp(S - m)
        #pragma unroll
        for (int rep = 0; rep < 16; ++rep) {
            const int idx = tid + rep * 256;
            const int r = idx >> 6, c = idx & 63;
            Ss[r][c] = expf(Ss[r][c] - mrow[r]);
        }
        __syncthreads();

        // row sum -> l update
        if (tid < 64) {
            float sum = 0.f;
            #pragma unroll 8
            for (int t = 0; t < 64; ++t) sum += Ss[tid][t];
            lrow[tid] = lrow[tid] * arow[tid] + sum;
        }

        // O = O*alpha + P @ V
        #pragma unroll
        for (int i = 0; i < 4; ++i) {
            const float al = arow[ty + 16 * i];
            #pragma unroll
            for (int j = 0; j < 4; ++j) O[i][j] *= al;
        }
        #pragma unroll 8
        for (int kk = 0; kk < 64; ++kk) {
            float pv[4], vv[4];
            #pragma unroll
            for (int i = 0; i < 4; ++i) pv[i] = Ss[ty + 16 * i][kk];
            #pragma unroll
            for (int j = 0; j < 4; ++j) vv[j] = Vs[kk][tx * 4 + j];
            #pragma unroll
            for (int i = 0; i < 4; ++i)
                #pragma unroll
                for (int j = 0; j < 4; ++j)
                    O[i][j] = fmaf(pv[i], vv[j], O[i][j]);
        }
        __syncthreads();   // protect Ks/Vs/Ss/arow/mrow for next iteration
    }

    // write head_out = O / l
    #pragma unroll
    for (int i = 0; i < 4; ++i) {
        const int row = ty + 16 * i;
        const float inv = 1.0f / lrow[row];
        float4 o4 = make_float4(O[i][0] * inv, O[i][1] * inv,
                                O[i][2] * inv, O[i][3] * inv);
        *(float4*)&HO[base + (size_t)(q0 + row) * Dm + tx * 4] = o4;
    }
}

// ---------------------------------------------------------------------------
extern "C" void kernel_launch(void* const* d_in, const int* in_sizes, int n_in,
                              void* d_out, int out_size, void* d_ws, size_t ws_size,
                              hipStream_t stream)
{
    const float* x  = (const float*)d_in[0];
    const float* Wq = (const float*)d_in[1];
    const float* Wk = (const float*)d_in[2];
    const float* Wv = (const float*)d_in[3];
    const float* Wo = (const float*)d_in[4];
    // d_in[5] = lambdas (zeros, unused by the reference math)
    float* out = (float*)d_out;

    const size_t mat = (size_t)Mrows * Dm;   // 8M floats = 32 MB
    float* Qp  = (float*)d_ws;
    float* Kp  = Qp + mat;
    float* Vp  = Kp + mat;
    float* HOp = Vp + mat;

    dim3 blk(256);
    // QKV projections + RoPE
    qkv_rope_kernel<<<dim3(Dm / 64, Mrows / 64, 3), blk, 0, stream>>>(
        x, Wq, Wk, Wv, Qp, Kp, Vp);
    // causal flash attention
    attn_kernel<<<dim3(Sq / 64, NH, Bsz), blk, 0, stream>>>(Qp, Kp, Vp, HOp);
    // output projection
    oproj_kernel<<<dim3(Dm / 64, Mrows / 64, 1), blk, 0, stream>>>(HOp, Wo, out);
}

// Round 2
// 1455.091 us; speedup vs baseline: 2.2803x; 2.2803x over previous
//
#include <hip/hip_runtime.h>
#include <math.h>

static constexpr int Bsz = 4, Sq = 2048, Dm = 1024, NH = 16, DHd = 64;
static constexpr int Mrows = Bsz * Sq;  // 8192
// ln(10000)/64
static constexpr float ROPE_LN = 0.14391156831212787f;

typedef _Float16 half8 __attribute__((ext_vector_type(8)));
typedef _Float16 half4v __attribute__((ext_vector_type(4)));
typedef float f32x4 __attribute__((ext_vector_type(4)));

// ---------------------------------------------------------------------------
// Tiled NT GEMM: C[m,n] = sum_k A[m,k] * W[n,k]  (A: M x K, W: N x K row-major)
// 64x64 tile per block, 256 threads, 4x4 micro-tile per thread.
// OutT = float (plain) or _Float16 (for Q/K/V feeding the MFMA attention).
// ---------------------------------------------------------------------------
template <typename OutT>
__device__ __forceinline__ void gemm_tile_nt(
    const float* __restrict__ A, const float* __restrict__ W,
    OutT* __restrict__ C, int K, int N, int do_rope)
{
    __shared__ float As[64][16];
    __shared__ float Bs[16][65];

    const int tid = threadIdx.x;
    const int tx = tid & 15, ty = tid >> 4;
    const int m0 = blockIdx.y * 64;
    const int n0 = blockIdx.x * 64;

    const int lr = tid >> 2;
    const int kc = (tid & 3) * 4;

    float acc[4][4] = {{0.f, 0.f, 0.f, 0.f}, {0.f, 0.f, 0.f, 0.f},
                       {0.f, 0.f, 0.f, 0.f}, {0.f, 0.f, 0.f, 0.f}};

    for (int k0 = 0; k0 < K; k0 += 16) {
        const float4 a4 = *(const float4*)&A[(size_t)(m0 + lr) * K + k0 + kc];
        const float4 w4 = *(const float4*)&W[(size_t)(n0 + lr) * K + k0 + kc];
        __syncthreads();
        *(float4*)&As[lr][kc] = a4;
        Bs[kc + 0][lr] = w4.x;
        Bs[kc + 1][lr] = w4.y;
        Bs[kc + 2][lr] = w4.z;
        Bs[kc + 3][lr] = w4.w;
        __syncthreads();

        #pragma unroll
        for (int kk = 0; kk < 16; ++kk) {
            float av[4], bv[4];
            #pragma unroll
            for (int i = 0; i < 4; ++i) av[i] = As[ty + 16 * i][kk];
            #pragma unroll
            for (int j = 0; j < 4; ++j) bv[j] = Bs[kk][tx * 4 + j];
            #pragma unroll
            for (int i = 0; i < 4; ++i)
                #pragma unroll
                for (int j = 0; j < 4; ++j)
                    acc[i][j] = fmaf(av[i], bv[j], acc[i][j]);
        }
    }

    const int nbase = n0 + tx * 4;
    #pragma unroll
    for (int i = 0; i < 4; ++i) {
        const int m = m0 + ty + 16 * i;
        float v0 = acc[i][0], v1 = acc[i][1], v2 = acc[i][2], v3 = acc[i][3];
        if (do_rope) {
            const float pos = (float)(m & (Sq - 1));
            const int dh0 = nbase & (DHd - 1);
            const float f0 = expf(-ROPE_LN * (float)dh0);
            const float f1 = expf(-ROPE_LN * (float)(dh0 + 2));
            const float a0 = pos * f0, a1 = pos * f1;
            const float c0 = cosf(a0), s0 = sinf(a0);
            const float c1 = cosf(a1), s1 = sinf(a1);
            const float e0 = v0 * c0 - v1 * s0, o0 = v0 * s0 + v1 * c0;
            const float e1 = v2 * c1 - v3 * s1, o1 = v2 * s1 + v3 * c1;
            v0 = e0; v1 = o0; v2 = e1; v3 = o1;
        }
        if constexpr (sizeof(OutT) == 4) {
            *(float4*)&C[(size_t)m * N + nbase] = make_float4(v0, v1, v2, v3);
        } else {
            half4v hv;
            hv[0] = (_Float16)v0; hv[1] = (_Float16)v1;
            hv[2] = (_Float16)v2; hv[3] = (_Float16)v3;
            *(half4v*)&C[(size_t)m * N + nbase] = hv;
        }
    }
}

__global__ __launch_bounds__(256) void qkv_rope_kernel(
    const float* __restrict__ x,
    const float* __restrict__ Wq, const float* __restrict__ Wk,
    const float* __restrict__ Wv,
    _Float16* __restrict__ Qo, _Float16* __restrict__ Ko,
    _Float16* __restrict__ Vo)
{
    const int z = blockIdx.z;
    const float* W = (z == 0) ? Wq : (z == 1) ? Wk : Wv;
    _Float16* C = (z == 0) ? Qo : (z == 1) ? Ko : Vo;
    gemm_tile_nt<_Float16>(x, W, C, Dm, Dm, (z < 2) ? 1 : 0);
}

__global__ __launch_bounds__(256) void oproj_kernel(
    const float* __restrict__ HO, const float* __restrict__ Wo,
    float* __restrict__ out)
{
    gemm_tile_nt<float>(HO, Wo, out, Dm, Dm, 0);
}

// ---------------------------------------------------------------------------
// MFMA flash attention (causal). Block = (b, h, 64-row Q tile), 4 waves.
// Wave w owns Q rows [w*16, w*16+16). mfma_f32_16x16x32_f16 layouts:
//   A: lane holds A[m=lane&15][k=quad*8+j]       (quad = lane>>4, j=0..7)
//   B: lane holds B[k=quad*8+j][n=lane&15]
//   C/D: lane reg r holds D[row=quad*4+r][col=lane&15]
// Softmax stats (m,l,alpha) live in registers, reduced by __shfl_xor over
// the 16 lanes of each quad. P transposes C-layout -> A-layout via
// wave-private LDS. V staged transposed with XOR swizzle (<=2-way conflicts).
// ---------------------------------------------------------------------------
__global__ __launch_bounds__(256) void attn_mfma_kernel(
    const _Float16* __restrict__ Q, const _Float16* __restrict__ K,
    const _Float16* __restrict__ V, float* __restrict__ HO)
{
    __shared__ _Float16 Qs[64][72];
    __shared__ _Float16 Ks[64][72];
    __shared__ _Float16 Vt[64 * 64];     // off = dh*64 + (t ^ swz(dh))
    __shared__ _Float16 Ps[4][16][72];   // per-wave P tile

    const int tid = threadIdx.x;
    const int wave = tid >> 6, lane = tid & 63;
    const int quad = lane >> 4, l16 = lane & 15;
    const int qi = blockIdx.x, h = blockIdx.y, b = blockIdx.z;
    const int q0 = qi * 64;
    const size_t base = (size_t)b * Sq * Dm + (size_t)h * DHd;

    const int sr = tid >> 2;            // staging row 0..63
    const int sc = (tid & 3) * 16;      // staging col 0/16/32/48

    // ---- stage Q tile (row-major, +8 pad) ----
    {
        const _Float16* src = Q + base + (size_t)(q0 + sr) * Dm + sc;
        *(float4*)&Qs[sr][sc] = *(const float4*)(src);
        *(float4*)&Qs[sr][sc + 8] = *(const float4*)(src + 8);
    }
    __syncthreads();

    half8 aQ[2];
    aQ[0] = *(const half8*)&Qs[wave * 16 + l16][quad * 8];
    aQ[1] = *(const half8*)&Qs[wave * 16 + l16][32 + quad * 8];

    f32x4 Oacc[4];
    #pragma unroll
    for (int nb = 0; nb < 4; ++nb)
        #pragma unroll
        for (int r = 0; r < 4; ++r) Oacc[nb][r] = 0.f;
    float mrow[4] = {-3.0e38f, -3.0e38f, -3.0e38f, -3.0e38f};
    float lrow[4] = {0.f, 0.f, 0.f, 0.f};

    for (int jt = 0; jt <= qi; ++jt) {
        const int t0 = jt * 64;
        __syncthreads();   // prior tile's Ks/Vt reads complete

        // ---- stage K tile ----
        {
            const _Float16* src = K + base + (size_t)(t0 + sr) * Dm + sc;
            *(float4*)&Ks[sr][sc] = *(const float4*)(src);
            *(float4*)&Ks[sr][sc + 8] = *(const float4*)(src + 8);
        }
        // ---- stage V transposed + swizzled: Vt[dh][t] ----
        {
            const _Float16* src = V + base + (size_t)(t0 + sr) * Dm + sc;
            _Float16 tmp[16];
            *(float4*)&tmp[0] = *(const float4*)(src);
            *(float4*)&tmp[8] = *(const float4*)(src + 8);
            #pragma unroll
            for (int i = 0; i < 16; ++i) {
                const int dh = sc + i;
                const int swz = (((dh & 7) ^ (((dh >> 4) & 3) << 1)) << 3);
                Vt[dh * 64 + (sr ^ swz)] = tmp[i];
            }
        }
        __syncthreads();

        // ---- S = Q K^T (8 MFMAs) ----
        f32x4 sacc[4];
        #pragma unroll
        for (int nb = 0; nb < 4; ++nb)
            #pragma unroll
            for (int r = 0; r < 4; ++r) sacc[nb][r] = 0.f;
        #pragma unroll
        for (int kstep = 0; kstep < 2; ++kstep) {
            #pragma unroll
            for (int nb = 0; nb < 4; ++nb) {
                const half8 bK =
                    *(const half8*)&Ks[nb * 16 + l16][kstep * 32 + quad * 8];
                sacc[nb] = __builtin_amdgcn_mfma_f32_16x16x32_f16(
                    aQ[kstep], bK, sacc[nb], 0, 0, 0);
            }
        }

        // ---- scale + causal mask (register C-layout) ----
        const bool diag = (jt == qi);
        float sv[4][4];
        #pragma unroll
        for (int nb = 0; nb < 4; ++nb)
            #pragma unroll
            for (int r = 0; r < 4; ++r) {
                float v = sacc[nb][r] * 0.125f;
                if (diag && (nb * 16 + l16 > wave * 16 + quad * 4 + r))
                    v = -3.0e38f;
                sv[nb][r] = v;
            }

        // ---- online softmax, all in registers ----
        float mx[4], alpha[4], rs[4];
        #pragma unroll
        for (int r = 0; r < 4; ++r) {
            mx[r] = fmaxf(fmaxf(sv[0][r], sv[1][r]), fmaxf(sv[2][r], sv[3][r]));
        }
        #pragma unroll
        for (int off = 8; off >= 1; off >>= 1)
            #pragma unroll
            for (int r = 0; r < 4; ++r)
                mx[r] = fmaxf(mx[r], __shfl_xor(mx[r], off));
        #pragma unroll
        for (int r = 0; r < 4; ++r) {
            const float mnew = fmaxf(mrow[r], mx[r]);
            alpha[r] = __expf(mrow[r] - mnew);
            mrow[r] = mnew;
            rs[r] = 0.f;
        }
        #pragma unroll
        for (int nb = 0; nb < 4; ++nb)
            #pragma unroll
            for (int r = 0; r < 4; ++r) {
                const float p = __expf(sv[nb][r] - mrow[r]);
                rs[r] += p;
                Ps[wave][quad * 4 + r][nb * 16 + l16] = (_Float16)p;
            }
        #pragma unroll
        for (int off = 8; off >= 1; off >>= 1)
            #pragma unroll
            for (int r = 0; r < 4; ++r)
                rs[r] += __shfl_xor(rs[r], off);
        #pragma unroll
        for (int r = 0; r < 4; ++r)
            lrow[r] = lrow[r] * alpha[r] + rs[r];
        #pragma unroll
        for (int nb = 0; nb < 4; ++nb)
            #pragma unroll
            for (int r = 0; r < 4; ++r) Oacc[nb][r] *= alpha[r];

        // ---- O += P V  (P via wave-private LDS transpose; 8 MFMAs) ----
        #pragma unroll
        for (int kstep = 0; kstep < 2; ++kstep) {
            const half8 aP = *(const half8*)&Ps[wave][l16][kstep * 32 + quad * 8];
            #pragma unroll
            for (int nb = 0; nb < 4; ++nb) {
                const int dh = nb * 16 + l16;
                const int swz = (((dh & 7) ^ (((dh >> 4) & 3) << 1)) << 3);
                const half8 bV =
                    *(const half8*)&Vt[dh * 64 + ((kstep * 32 + quad * 8) ^ swz)];
                Oacc[nb] = __builtin_amdgcn_mfma_f32_16x16x32_f16(
                    aP, bV, Oacc[nb], 0, 0, 0);
            }
        }
    }

    // ---- epilogue: HO = O / l ----
    float inv[4];
    #pragma unroll
    for (int r = 0; r < 4; ++r) inv[r] = 1.0f / lrow[r];
    #pragma unroll
    for (int nb = 0; nb < 4; ++nb)
        #pragma unroll
        for (int r = 0; r < 4; ++r) {
            const int row = wave * 16 + quad * 4 + r;
            HO[base + (size_t)(q0 + row) * Dm + nb * 16 + l16] =
                Oacc[nb][r] * inv[r];
        }
}

// ---------------------------------------------------------------------------
extern "C" void kernel_launch(void* const* d_in, const int* in_sizes, int n_in,
                              void* d_out, int out_size, void* d_ws, size_t ws_size,
                              hipStream_t stream)
{
    const float* x  = (const float*)d_in[0];
    const float* Wq = (const float*)d_in[1];
    const float* Wk = (const float*)d_in[2];
    const float* Wv = (const float*)d_in[3];
    const float* Wo = (const float*)d_in[4];
    float* out = (float*)d_out;

    const size_t mat = (size_t)Mrows * Dm;   // 8M elements
    _Float16* Qh = (_Float16*)d_ws;          // 16 MB
    _Float16* Kh = Qh + mat;                 // 16 MB
    _Float16* Vh = Kh + mat;                 // 16 MB
    float* HOp = (float*)(Vh + mat);         // 32 MB

    dim3 blk(256);
    qkv_rope_kernel<<<dim3(Dm / 64, Mrows / 64, 3), blk, 0, stream>>>(
        x, Wq, Wk, Wv, Qh, Kh, Vh);
    attn_mfma_kernel<<<dim3(Sq / 64, NH, Bsz), blk, 0, stream>>>(
        Qh, Kh, Vh, HOp);
    oproj_kernel<<<dim3(Dm / 64, Mrows / 64, 1), blk, 0, stream>>>(HOp, Wo, out);
}

// Round 3
// 496.019 us; speedup vs baseline: 6.6895x; 2.9335x over previous
//
#include <hip/hip_runtime.h>
#include <math.h>

static constexpr int Bsz = 4, Sq = 2048, Dm = 1024, NH = 16, DHd = 64;
static constexpr int Mrows = Bsz * Sq;  // 8192
// ln(10000)/64
static constexpr float ROPE_LN = 0.14391156831212787f;

typedef _Float16 half8 __attribute__((ext_vector_type(8)));
typedef _Float16 half4v __attribute__((ext_vector_type(4)));
typedef float f32x4 __attribute__((ext_vector_type(4)));

// async global->LDS, 16B per lane; LDS dest = wave-uniform base + lane*16
__device__ __forceinline__ void gl_lds16(const void* g, void* l) {
    __builtin_amdgcn_global_load_lds(
        (const __attribute__((address_space(1))) void*)g,
        (__attribute__((address_space(3))) void*)l, 16, 0, 0);
}

// ---------------------------------------------------------------------------
// helpers: fp32 -> fp16 cast, RoPE table
// ---------------------------------------------------------------------------
__global__ __launch_bounds__(256) void cast_f32_to_f16(
    const float* __restrict__ s, _Float16* __restrict__ d, int n4)
{
    const int i = blockIdx.x * 256 + threadIdx.x;
    if (i < n4) {
        const float4 v = ((const float4*)s)[i];
        half4v h;
        h[0] = (_Float16)v.x; h[1] = (_Float16)v.y;
        h[2] = (_Float16)v.z; h[3] = (_Float16)v.w;
        ((half4v*)d)[i] = h;
    }
}

__global__ __launch_bounds__(256) void rope_tab_kernel(float2* __restrict__ tab)
{
    const int t = blockIdx.x * 256 + threadIdx.x;   // Sq*32 total
    const int pos = t >> 5, j = t & 31;
    const float f = expf(-ROPE_LN * (float)(2 * j));
    const float a = (float)pos * f;
    tab[t] = make_float2(cosf(a), sinf(a));
}

// ---------------------------------------------------------------------------
// MFMA NT GEMM: C[m,n] = sum_k A[m,k]*W[n,k], A:MxK fp16, W:NxK fp16.
// 128x128 tile, 256 threads (4 waves 2x2), BK=32, 16x16x32_f16.
// Staging via global_load_lds w=16 with XOR chunk swizzle:
//   physical chunk(row,c) = row*4 + (c ^ ((row>>1)&3))
// -> wave-issue stays contiguous in LDS (HW constraint) AND fragment
//    ds_read_b128 lands 2-way-per-bank (free, m136).
// Optional RoPE epilogue (pairs exchanged via __shfl_xor lane^1).
// ---------------------------------------------------------------------------
template <typename OutT>
__device__ __forceinline__ void mfma_gemm_body(
    const _Float16* __restrict__ A, const _Float16* __restrict__ W,
    OutT* __restrict__ C, const float2* __restrict__ rope, int do_rope,
    int K, int N)
{
    __shared__ _Float16 As[128 * 32];
    __shared__ _Float16 Bs[128 * 32];

    const int tid = threadIdx.x;
    const int wave = tid >> 6, lane = tid & 63;
    const int quad = lane >> 4, l16 = lane & 15;
    const int wm = (wave >> 1) * 64, wn = (wave & 1) * 64;
    const int m0 = blockIdx.y * 128, n0 = blockIdx.x * 128;

    // staging descriptors: 2 wave-issues per operand, 64 chunks each
    const _Float16* gA[2]; const _Float16* gB[2];
    _Float16* lA[2]; _Float16* lB[2];
    #pragma unroll
    for (int i = 0; i < 2; ++i) {
        const int F = (wave * 2 + i) * 64 + lane;   // physical chunk index
        const int r = F >> 2, cp = F & 3;
        const int c = cp ^ ((r >> 1) & 3);          // logical k-chunk
        gA[i] = A + (size_t)(m0 + r) * K + c * 8;
        gB[i] = W + (size_t)(n0 + r) * K + c * 8;
        lA[i] = As + (wave * 2 + i) * 512;          // uniform base (64 chunks)
        lB[i] = Bs + (wave * 2 + i) * 512;
    }

    // fragment read offsets (halves)
    const int sw = (l16 >> 1) & 3;
    int offA[4], offB[4];
    #pragma unroll
    for (int t = 0; t < 4; ++t) {
        const int rA = wm + t * 16 + l16;
        offA[t] = rA * 32 + ((quad ^ sw) * 8);
        const int rB = wn + t * 16 + l16;
        offB[t] = rB * 32 + ((quad ^ sw) * 8);
    }

    f32x4 acc[4][4];
    #pragma unroll
    for (int im = 0; im < 4; ++im)
        #pragma unroll
        for (int nb = 0; nb < 4; ++nb)
            #pragma unroll
            for (int r = 0; r < 4; ++r) acc[im][nb][r] = 0.f;

    for (int k0 = 0; k0 < K; k0 += 32) {
        __syncthreads();   // prior iteration's ds_reads complete
        #pragma unroll
        for (int i = 0; i < 2; ++i) {
            gl_lds16(gA[i] + k0, lA[i]);
            gl_lds16(gB[i] + k0, lB[i]);
        }
        __syncthreads();   // staging landed

        half8 a[4], b[4];
        #pragma unroll
        for (int t = 0; t < 4; ++t) {
            a[t] = *(const half8*)&As[offA[t]];
            b[t] = *(const half8*)&Bs[offB[t]];
        }
        #pragma unroll
        for (int im = 0; im < 4; ++im)
            #pragma unroll
            for (int nb = 0; nb < 4; ++nb)
                acc[im][nb] = __builtin_amdgcn_mfma_f32_16x16x32_f16(
                    a[im], b[nb], acc[im][nb], 0, 0, 0);
    }

    // ---- epilogue ----
    #pragma unroll
    for (int nb = 0; nb < 4; ++nb) {
        const int n = n0 + wn + nb * 16 + l16;
        const int j = (n & 63) >> 1;
        #pragma unroll
        for (int im = 0; im < 4; ++im) {
            #pragma unroll
            for (int r = 0; r < 4; ++r) {
                const int m = m0 + wm + im * 16 + quad * 4 + r;
                float v = acc[im][nb][r];
                if (do_rope) {
                    const int pos = m & (Sq - 1);
                    const float2 cs = rope[pos * 32 + j];
                    const float vp = __shfl_xor(v, 1);
                    v = (n & 1) ? (vp * cs.y + v * cs.x)
                                : (v * cs.x - vp * cs.y);
                }
                if constexpr (sizeof(OutT) == 4)
                    C[(size_t)m * N + n] = v;
                else
                    C[(size_t)m * N + n] = (_Float16)v;
            }
        }
    }
}

__global__ __launch_bounds__(256) void qkv_mfma_kernel(
    const _Float16* __restrict__ xh,
    const _Float16* __restrict__ Wq, const _Float16* __restrict__ Wk,
    const _Float16* __restrict__ Wv,
    _Float16* __restrict__ Qo, _Float16* __restrict__ Ko,
    _Float16* __restrict__ Vo, const float2* __restrict__ rope)
{
    const int z = blockIdx.z;
    const _Float16* W = (z == 0) ? Wq : (z == 1) ? Wk : Wv;
    _Float16* C = (z == 0) ? Qo : (z == 1) ? Ko : Vo;
    mfma_gemm_body<_Float16>(xh, W, C, rope, (z < 2) ? 1 : 0, Dm, Dm);
}

__global__ __launch_bounds__(256) void oproj_mfma_kernel(
    const _Float16* __restrict__ HOh, const _Float16* __restrict__ Wo,
    float* __restrict__ out)
{
    mfma_gemm_body<float>(HOh, Wo, out, nullptr, 0, Dm, Dm);
}

// ---------------------------------------------------------------------------
// MFMA flash attention (causal), unchanged from R2 except fp16 output.
// ---------------------------------------------------------------------------
__global__ __launch_bounds__(256) void attn_mfma_kernel(
    const _Float16* __restrict__ Q, const _Float16* __restrict__ K,
    const _Float16* __restrict__ V, _Float16* __restrict__ HO)
{
    __shared__ _Float16 Qs[64][72];
    __shared__ _Float16 Ks[64][72];
    __shared__ _Float16 Vt[64 * 64];
    __shared__ _Float16 Ps[4][16][72];

    const int tid = threadIdx.x;
    const int wave = tid >> 6, lane = tid & 63;
    const int quad = lane >> 4, l16 = lane & 15;
    const int qi = blockIdx.x, h = blockIdx.y, b = blockIdx.z;
    const int q0 = qi * 64;
    const size_t base = (size_t)b * Sq * Dm + (size_t)h * DHd;

    const int sr = tid >> 2;
    const int sc = (tid & 3) * 16;

    {
        const _Float16* src = Q + base + (size_t)(q0 + sr) * Dm + sc;
        *(float4*)&Qs[sr][sc] = *(const float4*)(src);
        *(float4*)&Qs[sr][sc + 8] = *(const float4*)(src + 8);
    }
    __syncthreads();

    half8 aQ[2];
    aQ[0] = *(const half8*)&Qs[wave * 16 + l16][quad * 8];
    aQ[1] = *(const half8*)&Qs[wave * 16 + l16][32 + quad * 8];

    f32x4 Oacc[4];
    #pragma unroll
    for (int nb = 0; nb < 4; ++nb)
        #pragma unroll
        for (int r = 0; r < 4; ++r) Oacc[nb][r] = 0.f;
    float mrow[4] = {-3.0e38f, -3.0e38f, -3.0e38f, -3.0e38f};
    float lrow[4] = {0.f, 0.f, 0.f, 0.f};

    for (int jt = 0; jt <= qi; ++jt) {
        const int t0 = jt * 64;
        __syncthreads();

        {
            const _Float16* src = K + base + (size_t)(t0 + sr) * Dm + sc;
            *(float4*)&Ks[sr][sc] = *(const float4*)(src);
            *(float4*)&Ks[sr][sc + 8] = *(const float4*)(src + 8);
        }
        {
            const _Float16* src = V + base + (size_t)(t0 + sr) * Dm + sc;
            _Float16 tmp[16];
            *(float4*)&tmp[0] = *(const float4*)(src);
            *(float4*)&tmp[8] = *(const float4*)(src + 8);
            #pragma unroll
            for (int i = 0; i < 16; ++i) {
                const int dh = sc + i;
                const int swz = (((dh & 7) ^ (((dh >> 4) & 3) << 1)) << 3);
                Vt[dh * 64 + (sr ^ swz)] = tmp[i];
            }
        }
        __syncthreads();

        f32x4 sacc[4];
        #pragma unroll
        for (int nb = 0; nb < 4; ++nb)
            #pragma unroll
            for (int r = 0; r < 4; ++r) sacc[nb][r] = 0.f;
        #pragma unroll
        for (int kstep = 0; kstep < 2; ++kstep) {
            #pragma unroll
            for (int nb = 0; nb < 4; ++nb) {
                const half8 bK =
                    *(const half8*)&Ks[nb * 16 + l16][kstep * 32 + quad * 8];
                sacc[nb] = __builtin_amdgcn_mfma_f32_16x16x32_f16(
                    aQ[kstep], bK, sacc[nb], 0, 0, 0);
            }
        }

        const bool diag = (jt == qi);
        float sv[4][4];
        #pragma unroll
        for (int nb = 0; nb < 4; ++nb)
            #pragma unroll
            for (int r = 0; r < 4; ++r) {
                float v = sacc[nb][r] * 0.125f;
                if (diag && (nb * 16 + l16 > wave * 16 + quad * 4 + r))
                    v = -3.0e38f;
                sv[nb][r] = v;
            }

        float mx[4], alpha[4], rs[4];
        #pragma unroll
        for (int r = 0; r < 4; ++r)
            mx[r] = fmaxf(fmaxf(sv[0][r], sv[1][r]), fmaxf(sv[2][r], sv[3][r]));
        #pragma unroll
        for (int off = 8; off >= 1; off >>= 1)
            #pragma unroll
            for (int r = 0; r < 4; ++r)
                mx[r] = fmaxf(mx[r], __shfl_xor(mx[r], off));
        #pragma unroll
        for (int r = 0; r < 4; ++r) {
            const float mnew = fmaxf(mrow[r], mx[r]);
            alpha[r] = __expf(mrow[r] - mnew);
            mrow[r] = mnew;
            rs[r] = 0.f;
        }
        #pragma unroll
        for (int nb = 0; nb < 4; ++nb)
            #pragma unroll
            for (int r = 0; r < 4; ++r) {
                const float p = __expf(sv[nb][r] - mrow[r]);
                rs[r] += p;
                Ps[wave][quad * 4 + r][nb * 16 + l16] = (_Float16)p;
            }
        #pragma unroll
        for (int off = 8; off >= 1; off >>= 1)
            #pragma unroll
            for (int r = 0; r < 4; ++r)
                rs[r] += __shfl_xor(rs[r], off);
        #pragma unroll
        for (int r = 0; r < 4; ++r)
            lrow[r] = lrow[r] * alpha[r] + rs[r];
        #pragma unroll
        for (int nb = 0; nb < 4; ++nb)
            #pragma unroll
            for (int r = 0; r < 4; ++r) Oacc[nb][r] *= alpha[r];

        #pragma unroll
        for (int kstep = 0; kstep < 2; ++kstep) {
            const half8 aP = *(const half8*)&Ps[wave][l16][kstep * 32 + quad * 8];
            #pragma unroll
            for (int nb = 0; nb < 4; ++nb) {
                const int dh = nb * 16 + l16;
                const int swz = (((dh & 7) ^ (((dh >> 4) & 3) << 1)) << 3);
                const half8 bV =
                    *(const half8*)&Vt[dh * 64 + ((kstep * 32 + quad * 8) ^ swz)];
                Oacc[nb] = __builtin_amdgcn_mfma_f32_16x16x32_f16(
                    aP, bV, Oacc[nb], 0, 0, 0);
            }
        }
    }

    float inv[4];
    #pragma unroll
    for (int r = 0; r < 4; ++r) inv[r] = 1.0f / lrow[r];
    #pragma unroll
    for (int nb = 0; nb < 4; ++nb)
        #pragma unroll
        for (int r = 0; r < 4; ++r) {
            const int row = wave * 16 + quad * 4 + r;
            HO[base + (size_t)(q0 + row) * Dm + nb * 16 + l16] =
                (_Float16)(Oacc[nb][r] * inv[r]);
        }
}

// ---------------------------------------------------------------------------
extern "C" void kernel_launch(void* const* d_in, const int* in_sizes, int n_in,
                              void* d_out, int out_size, void* d_ws, size_t ws_size,
                              hipStream_t stream)
{
    const float* x  = (const float*)d_in[0];
    const float* Wq = (const float*)d_in[1];
    const float* Wk = (const float*)d_in[2];
    const float* Wv = (const float*)d_in[3];
    const float* Wo = (const float*)d_in[4];
    float* out = (float*)d_out;

    const size_t matX = (size_t)Mrows * Dm;   // 8.4M elements
    const size_t matW = (size_t)Dm * Dm;      // 1.05M elements

    _Float16* xh  = (_Float16*)d_ws;
    _Float16* Wqh = xh + matX;
    _Float16* Wkh = Wqh + matW;
    _Float16* Wvh = Wkh + matW;
    _Float16* Woh = Wvh + matW;
    _Float16* Qh  = Woh + matW;
    _Float16* Kh  = Qh + matX;
    _Float16* Vh  = Kh + matX;
    _Float16* HOh = Vh + matX;
    float2* rope  = (float2*)(HOh + matX);    // Sq*32 entries

    dim3 blk(256);
    cast_f32_to_f16<<<(int)(matX / 4 / 256), blk, 0, stream>>>(x, xh, (int)(matX / 4));
    cast_f32_to_f16<<<(int)(matW / 4 / 256), blk, 0, stream>>>(Wq, Wqh, (int)(matW / 4));
    cast_f32_to_f16<<<(int)(matW / 4 / 256), blk, 0, stream>>>(Wk, Wkh, (int)(matW / 4));
    cast_f32_to_f16<<<(int)(matW / 4 / 256), blk, 0, stream>>>(Wv, Wvh, (int)(matW / 4));
    cast_f32_to_f16<<<(int)(matW / 4 / 256), blk, 0, stream>>>(Wo, Woh, (int)(matW / 4));
    rope_tab_kernel<<<Sq * 32 / 256, blk, 0, stream>>>(rope);

    qkv_mfma_kernel<<<dim3(Dm / 128, Mrows / 128, 3), blk, 0, stream>>>(
        xh, Wqh, Wkh, Wvh, Qh, Kh, Vh, rope);
    attn_mfma_kernel<<<dim3(Sq / 64, NH, Bsz), blk, 0, stream>>>(Qh, Kh, Vh, HOh);
    oproj_mfma_kernel<<<dim3(Dm / 128, Mrows / 128, 1), blk, 0, stream>>>(
        HOh, Woh, out);
}

// Round 4
// 379.005 us; speedup vs baseline: 8.7548x; 1.3087x over previous
//
#include <hip/hip_runtime.h>
#include <math.h>

static constexpr int Bsz = 4, Sq = 2048, Dm = 1024, NH = 16, DHd = 64;
static constexpr int Mrows = Bsz * Sq;  // 8192
// ln(10000)/64
static constexpr float ROPE_LN = 0.14391156831212787f;

typedef _Float16 half8 __attribute__((ext_vector_type(8)));
typedef _Float16 half4v __attribute__((ext_vector_type(4)));
typedef float f32x4 __attribute__((ext_vector_type(4)));

// async global->LDS, 16B per lane; LDS dest = wave-uniform base + lane*16
__device__ __forceinline__ void gl_lds16(const void* g, void* l) {
    __builtin_amdgcn_global_load_lds(
        (const __attribute__((address_space(1))) void*)g,
        (__attribute__((address_space(3))) void*)l, 16, 0, 0);
}

// ---------------------------------------------------------------------------
// Fused prep: cast x + 4 weights to fp16, build RoPE table.
// Segment map over float4 index i:
//   [0, 2097152)            : x        (8192*1024 /4)
//   [2097152, 3145728)      : W[(i-2097152)>>18], off = & 262143
//   [3145728, 3211264)      : rope entry t = i - 3145728
// ---------------------------------------------------------------------------
__global__ __launch_bounds__(256) void prep_kernel(
    const float* __restrict__ x,
    const float* __restrict__ Wq, const float* __restrict__ Wk,
    const float* __restrict__ Wv, const float* __restrict__ Wo,
    _Float16* __restrict__ xh,
    _Float16* __restrict__ Wqh, _Float16* __restrict__ Wkh,
    _Float16* __restrict__ Wvh, _Float16* __restrict__ Woh,
    float2* __restrict__ rope)
{
    const int i = blockIdx.x * 256 + threadIdx.x;
    if (i < 2097152) {
        const float4 v = ((const float4*)x)[i];
        half4v hv;
        hv[0] = (_Float16)v.x; hv[1] = (_Float16)v.y;
        hv[2] = (_Float16)v.z; hv[3] = (_Float16)v.w;
        ((half4v*)xh)[i] = hv;
    } else if (i < 3145728) {
        const int w = (i - 2097152) >> 18;
        const int off = (i - 2097152) & 262143;
        const float* s = (w == 0) ? Wq : (w == 1) ? Wk : (w == 2) ? Wv : Wo;
        _Float16* d = (w == 0) ? Wqh : (w == 1) ? Wkh : (w == 2) ? Wvh : Woh;
        const float4 v = ((const float4*)s)[off];
        half4v hv;
        hv[0] = (_Float16)v.x; hv[1] = (_Float16)v.y;
        hv[2] = (_Float16)v.z; hv[3] = (_Float16)v.w;
        ((half4v*)d)[off] = hv;
    } else {
        const int t = i - 3145728;   // < 65536 by grid size
        const int pos = t >> 5, j = t & 31;
        const float f = expf(-ROPE_LN * (float)(2 * j));
        const float a = (float)pos * f;
        rope[t] = make_float2(cosf(a), sinf(a));
    }
}

// ---------------------------------------------------------------------------
// MFMA NT GEMM (unchanged from R3): 128x128 tile, BK=32, global_load_lds
// staging with XOR chunk swizzle, optional fused RoPE epilogue.
// ---------------------------------------------------------------------------
template <typename OutT>
__device__ __forceinline__ void mfma_gemm_body(
    const _Float16* __restrict__ A, const _Float16* __restrict__ W,
    OutT* __restrict__ C, const float2* __restrict__ rope, int do_rope,
    int K, int N)
{
    __shared__ _Float16 As[128 * 32];
    __shared__ _Float16 Bs[128 * 32];

    const int tid = threadIdx.x;
    const int wave = tid >> 6, lane = tid & 63;
    const int quad = lane >> 4, l16 = lane & 15;
    const int wm = (wave >> 1) * 64, wn = (wave & 1) * 64;
    const int m0 = blockIdx.y * 128, n0 = blockIdx.x * 128;

    const _Float16* gA[2]; const _Float16* gB[2];
    _Float16* lA[2]; _Float16* lB[2];
    #pragma unroll
    for (int i = 0; i < 2; ++i) {
        const int F = (wave * 2 + i) * 64 + lane;
        const int r = F >> 2, cp = F & 3;
        const int c = cp ^ ((r >> 1) & 3);
        gA[i] = A + (size_t)(m0 + r) * K + c * 8;
        gB[i] = W + (size_t)(n0 + r) * K + c * 8;
        lA[i] = As + (wave * 2 + i) * 512;
        lB[i] = Bs + (wave * 2 + i) * 512;
    }

    const int sw = (l16 >> 1) & 3;
    int offA[4], offB[4];
    #pragma unroll
    for (int t = 0; t < 4; ++t) {
        offA[t] = (wm + t * 16 + l16) * 32 + ((quad ^ sw) * 8);
        offB[t] = (wn + t * 16 + l16) * 32 + ((quad ^ sw) * 8);
    }

    f32x4 acc[4][4];
    #pragma unroll
    for (int im = 0; im < 4; ++im)
        #pragma unroll
        for (int nb = 0; nb < 4; ++nb)
            #pragma unroll
            for (int r = 0; r < 4; ++r) acc[im][nb][r] = 0.f;

    for (int k0 = 0; k0 < K; k0 += 32) {
        __syncthreads();
        #pragma unroll
        for (int i = 0; i < 2; ++i) {
            gl_lds16(gA[i] + k0, lA[i]);
            gl_lds16(gB[i] + k0, lB[i]);
        }
        __syncthreads();

        half8 a[4], b[4];
        #pragma unroll
        for (int t = 0; t < 4; ++t) {
            a[t] = *(const half8*)&As[offA[t]];
            b[t] = *(const half8*)&Bs[offB[t]];
        }
        #pragma unroll
        for (int im = 0; im < 4; ++im)
            #pragma unroll
            for (int nb = 0; nb < 4; ++nb)
                acc[im][nb] = __builtin_amdgcn_mfma_f32_16x16x32_f16(
                    a[im], b[nb], acc[im][nb], 0, 0, 0);
    }

    #pragma unroll
    for (int nb = 0; nb < 4; ++nb) {
        const int n = n0 + wn + nb * 16 + l16;
        const int j = (n & 63) >> 1;
        #pragma unroll
        for (int im = 0; im < 4; ++im) {
            #pragma unroll
            for (int r = 0; r < 4; ++r) {
                const int m = m0 + wm + im * 16 + quad * 4 + r;
                float v = acc[im][nb][r];
                if (do_rope) {
                    const int pos = m & (Sq - 1);
                    const float2 cs = rope[pos * 32 + j];
                    const float vp = __shfl_xor(v, 1);
                    v = (n & 1) ? (vp * cs.y + v * cs.x)
                                : (v * cs.x - vp * cs.y);
                }
                if constexpr (sizeof(OutT) == 4)
                    C[(size_t)m * N + n] = v;
                else
                    C[(size_t)m * N + n] = (_Float16)v;
            }
        }
    }
}

__global__ __launch_bounds__(256) void qkv_mfma_kernel(
    const _Float16* __restrict__ xh,
    const _Float16* __restrict__ Wq, const _Float16* __restrict__ Wk,
    const _Float16* __restrict__ Wv,
    _Float16* __restrict__ Qo, _Float16* __restrict__ Ko,
    _Float16* __restrict__ Vo, const float2* __restrict__ rope)
{
    const int z = blockIdx.z;
    const _Float16* W = (z == 0) ? Wq : (z == 1) ? Wk : Wv;
    _Float16* C = (z == 0) ? Qo : (z == 1) ? Ko : Vo;
    mfma_gemm_body<_Float16>(xh, W, C, rope, (z < 2) ? 1 : 0, Dm, Dm);
}

__global__ __launch_bounds__(256) void oproj_mfma_kernel(
    const _Float16* __restrict__ HOh, const _Float16* __restrict__ Wo,
    float* __restrict__ out)
{
    mfma_gemm_body<float>(HOh, Wo, out, nullptr, 0, Dm, Dm);
}

// ---------------------------------------------------------------------------
// MFMA flash attention v2 (causal):
//  * work-balanced pairing: block p handles Q-tiles p and 31-p (33 K-tiles)
//  * K staged via global_load_lds w=16 + XOR chunk swizzle (no pad,
//    conflict-free-minimum fragment reads)
//  * Q fragments loaded directly global->reg (no Qs) — LDS 25.6 KB,
//    6 blocks/CU
// ---------------------------------------------------------------------------
__global__ __launch_bounds__(256) void attn_mfma_kernel(
    const _Float16* __restrict__ Q, const _Float16* __restrict__ K,
    const _Float16* __restrict__ V, _Float16* __restrict__ HO)
{
    __shared__ _Float16 Ks[64 * 64];     // swizzled: row*64 + (c^(row&7))*8+j
    __shared__ _Float16 Vt[64 * 64];     // transposed: dh*64 + (t ^ swz(dh))
    __shared__ _Float16 Ps[4][16][72];   // per-wave P tile

    const int tid = threadIdx.x;
    const int wave = tid >> 6, lane = tid & 63;
    const int quad = lane >> 4, l16 = lane & 15;
    const int p = blockIdx.x, h = blockIdx.y, b = blockIdx.z;
    const size_t base = (size_t)b * Sq * Dm + (size_t)h * DHd;

    const int sr = tid >> 2;            // V staging row 0..63
    const int sc = (tid & 3) * 16;      // V staging col 0/16/32/48

    #pragma unroll
    for (int half = 0; half < 2; ++half) {
        const int qi = half ? (31 - p) : p;
        const int q0 = qi * 64;

        // Q fragments straight from global (once per Q-tile)
        half8 aQ[2];
        {
            const _Float16* qrow =
                Q + base + (size_t)(q0 + wave * 16 + l16) * Dm + quad * 8;
            aQ[0] = *(const half8*)(qrow);
            aQ[1] = *(const half8*)(qrow + 32);
        }

        f32x4 Oacc[4];
        #pragma unroll
        for (int nb = 0; nb < 4; ++nb)
            #pragma unroll
            for (int r = 0; r < 4; ++r) Oacc[nb][r] = 0.f;
        float mrow[4] = {-3.0e38f, -3.0e38f, -3.0e38f, -3.0e38f};
        float lrow[4] = {0.f, 0.f, 0.f, 0.f};

        for (int jt = 0; jt <= qi; ++jt) {
            const int t0 = jt * 64;
            __syncthreads();   // prior tile's LDS reads complete

            // ---- stage K via global_load_lds + XOR swizzle ----
            #pragma unroll
            for (int i = 0; i < 2; ++i) {
                const int F = (wave * 2 + i) * 64 + lane;
                const int kr = F >> 3;
                const int kcl = (F & 7) ^ (kr & 7);
                gl_lds16(K + base + (size_t)(t0 + kr) * Dm + kcl * 8,
                         Ks + (wave * 2 + i) * 512);
            }
            // ---- stage V transposed + swizzled ----
            {
                const _Float16* src = V + base + (size_t)(t0 + sr) * Dm + sc;
                _Float16 tmp[16];
                *(float4*)&tmp[0] = *(const float4*)(src);
                *(float4*)&tmp[8] = *(const float4*)(src + 8);
                #pragma unroll
                for (int i = 0; i < 16; ++i) {
                    const int dh = sc + i;
                    const int swz = (((dh & 7) ^ (((dh >> 4) & 3) << 1)) << 3);
                    Vt[dh * 64 + (sr ^ swz)] = tmp[i];
                }
            }
            __syncthreads();

            // ---- S = Q K^T (8 MFMAs) ----
            f32x4 sacc[4];
            #pragma unroll
            for (int nb = 0; nb < 4; ++nb)
                #pragma unroll
                for (int r = 0; r < 4; ++r) sacc[nb][r] = 0.f;
            #pragma unroll
            for (int kstep = 0; kstep < 2; ++kstep) {
                #pragma unroll
                for (int nb = 0; nb < 4; ++nb) {
                    const int krow = nb * 16 + l16;
                    const int kch = (kstep * 4 + quad) ^ (krow & 7);
                    const half8 bK = *(const half8*)&Ks[krow * 64 + kch * 8];
                    sacc[nb] = __builtin_amdgcn_mfma_f32_16x16x32_f16(
                        aQ[kstep], bK, sacc[nb], 0, 0, 0);
                }
            }

            // ---- scale + causal mask ----
            const bool diag = (jt == qi);
            float sv[4][4];
            #pragma unroll
            for (int nb = 0; nb < 4; ++nb)
                #pragma unroll
                for (int r = 0; r < 4; ++r) {
                    float v = sacc[nb][r] * 0.125f;
                    if (diag && (nb * 16 + l16 > wave * 16 + quad * 4 + r))
                        v = -3.0e38f;
                    sv[nb][r] = v;
                }

            // ---- online softmax (registers + quad shuffles) ----
            float mx[4], alpha[4], rs[4];
            #pragma unroll
            for (int r = 0; r < 4; ++r)
                mx[r] = fmaxf(fmaxf(sv[0][r], sv[1][r]),
                              fmaxf(sv[2][r], sv[3][r]));
            #pragma unroll
            for (int off = 8; off >= 1; off >>= 1)
                #pragma unroll
                for (int r = 0; r < 4; ++r)
                    mx[r] = fmaxf(mx[r], __shfl_xor(mx[r], off));
            #pragma unroll
            for (int r = 0; r < 4; ++r) {
                const float mnew = fmaxf(mrow[r], mx[r]);
                alpha[r] = __expf(mrow[r] - mnew);
                mrow[r] = mnew;
                rs[r] = 0.f;
            }
            #pragma unroll
            for (int nb = 0; nb < 4; ++nb)
                #pragma unroll
                for (int r = 0; r < 4; ++r) {
                    const float pv = __expf(sv[nb][r] - mrow[r]);
                    rs[r] += pv;
                    Ps[wave][quad * 4 + r][nb * 16 + l16] = (_Float16)pv;
                }
            #pragma unroll
            for (int off = 8; off >= 1; off >>= 1)
                #pragma unroll
                for (int r = 0; r < 4; ++r)
                    rs[r] += __shfl_xor(rs[r], off);
            #pragma unroll
            for (int r = 0; r < 4; ++r)
                lrow[r] = lrow[r] * alpha[r] + rs[r];
            #pragma unroll
            for (int nb = 0; nb < 4; ++nb)
                #pragma unroll
                for (int r = 0; r < 4; ++r) Oacc[nb][r] *= alpha[r];

            // ---- O += P V ----
            #pragma unroll
            for (int kstep = 0; kstep < 2; ++kstep) {
                const half8 aP =
                    *(const half8*)&Ps[wave][l16][kstep * 32 + quad * 8];
                #pragma unroll
                for (int nb = 0; nb < 4; ++nb) {
                    const int dh = nb * 16 + l16;
                    const int swz = (((dh & 7) ^ (((dh >> 4) & 3) << 1)) << 3);
                    const half8 bV = *(const half8*)
                        &Vt[dh * 64 + ((kstep * 32 + quad * 8) ^ swz)];
                    Oacc[nb] = __builtin_amdgcn_mfma_f32_16x16x32_f16(
                        aP, bV, Oacc[nb], 0, 0, 0);
                }
            }
        }

        // ---- epilogue: HO = O / l (fp16) ----
        float inv[4];
        #pragma unroll
        for (int r = 0; r < 4; ++r) inv[r] = 1.0f / lrow[r];
        #pragma unroll
        for (int nb = 0; nb < 4; ++nb)
            #pragma unroll
            for (int r = 0; r < 4; ++r) {
                const int row = wave * 16 + quad * 4 + r;
                HO[base + (size_t)(q0 + row) * Dm + nb * 16 + l16] =
                    (_Float16)(Oacc[nb][r] * inv[r]);
            }
    }
}

// ---------------------------------------------------------------------------
extern "C" void kernel_launch(void* const* d_in, const int* in_sizes, int n_in,
                              void* d_out, int out_size, void* d_ws, size_t ws_size,
                              hipStream_t stream)
{
    const float* x  = (const float*)d_in[0];
    const float* Wq = (const float*)d_in[1];
    const float* Wk = (const float*)d_in[2];
    const float* Wv = (const float*)d_in[3];
    const float* Wo = (const float*)d_in[4];
    float* out = (float*)d_out;

    const size_t matX = (size_t)Mrows * Dm;
    const size_t matW = (size_t)Dm * Dm;

    _Float16* xh  = (_Float16*)d_ws;
    _Float16* Wqh = xh + matX;
    _Float16* Wkh = Wqh + matW;
    _Float16* Wvh = Wkh + matW;
    _Float16* Woh = Wvh + matW;
    _Float16* Qh  = Woh + matW;
    _Float16* Kh  = Qh + matX;
    _Float16* Vh  = Kh + matX;
    _Float16* HOh = Vh + matX;
    float2* rope  = (float2*)(HOh + matX);    // Sq*32 entries

    dim3 blk(256);
    prep_kernel<<<(3145728 + 65536) / 256, blk, 0, stream>>>(
        x, Wq, Wk, Wv, Wo, xh, Wqh, Wkh, Wvh, Woh, rope);
    qkv_mfma_kernel<<<dim3(Dm / 128, Mrows / 128, 3), blk, 0, stream>>>(
        xh, Wqh, Wkh, Wvh, Qh, Kh, Vh, rope);
    attn_mfma_kernel<<<dim3(Sq / 128, NH, Bsz), blk, 0, stream>>>(
        Qh, Kh, Vh, HOh);
    oproj_mfma_kernel<<<dim3(Dm / 128, Mrows / 128, 1), blk, 0, stream>>>(
        HOh, Woh, out);
}